// Round 4
// baseline (1924.907 us; speedup 1.0000x reference)
//
#include <hip/hip_runtime.h>
#include <hip/hip_fp16.h>

#define DEV_INLINE __device__ __forceinline__

static DEV_INLINE float4 ld4(const float* p){ return *reinterpret_cast<const float4*>(p); }

#define GNUM 64
#define SCHUNK 16384
#define MAXNB4 2048   // (N/128)*4 must fit -> N <= 65536 (packing also needs N < 65536)

static DEV_INLINE int tile_of(int s, int TS){
    int t = 0;
    if (s >= TS)   t = 1;
    if (s >= 2*TS) t = 2;
    if (s >= 3*TS) t = 3;
    return t;
}
// layer-1 (D=128) swizzle: half-position p <-> column c
static DEV_INLINE int colmap1(int p){ return 16*(p&7) + (p>>3); }
static DEV_INLINE int pos1(int c){ return 8*(c&15) + (c>>4); }
// layer-2 (D=32) swizzle
static DEV_INLINE int colmap2(int p){ return 8*(p&3) + (p>>2); }
static DEV_INLINE int pos2(int c){ return 4*(c&7) + (c>>3); }

// ======================= edge-bucket build (no CSR, no global atomics) =======================
// key = (dst>>7)*4 + tile(src). Per-chunk local histograms -> exact two-level
// exclusive scan over [key][chunk] -> every chunk knows its exact write base.

__global__ __launch_bounds__(512) void k_hist(const int* __restrict__ src, const int* __restrict__ dst,
                                              int E, int NB4, int NBLK, int TS, int* __restrict__ cntg){
    __shared__ int cnt[MAXNB4];
    int t = threadIdx.x, blk = blockIdx.x;
    for (int i=t;i<NB4;i+=512) cnt[i]=0;
    __syncthreads();
    int base0 = blk*SCHUNK;
    int tot = E - base0; if (tot > SCHUNK) tot = SCHUNK;
    for (int o=t;o<tot;o+=512){
        int e = base0 + o;
        int key = ((dst[e]>>7)<<2) | tile_of(src[e], TS);
        atomicAdd(&cnt[key], 1);
    }
    __syncthreads();
    for (int i=t;i<NB4;i+=512) cntg[i*NBLK + blk] = cnt[i];  // key-major
}

// block-wise exclusive scan, 2048 elems/block (256 thr x 8)
__global__ void k_scanA(const int* __restrict__ in, int* __restrict__ out,
                        int* __restrict__ bsum, int M){
    __shared__ int ws[4];
    int t = threadIdx.x;
    int base = blockIdx.x*2048 + t*8;
    int v[8]; int tsum = 0;
    #pragma unroll
    for (int i=0;i<8;i++){ v[i] = (base+i<M)? in[base+i] : 0; tsum += v[i]; }
    int lane=t&63, w=t>>6, x=tsum;
    for (int off=1;off<64;off<<=1){ int yv=__shfl_up(x,off); if (lane>=off) x+=yv; }
    if (lane==63) ws[w]=x;
    __syncthreads();
    if (t==0){ int a=0; for (int i=0;i<4;i++){ int tmp=ws[i]; ws[i]=a; a+=tmp; } }
    __syncthreads();
    int ex = x - tsum + ws[w];
    #pragma unroll
    for (int i=0;i<8;i++){ if (base+i<M) out[base+i]=ex; ex += v[i]; }
    if (t==255) bsum[blockIdx.x] = ws[3] + x;
}

// in-place single-block exclusive scan, M <= 2048 (reads complete before barrier, writes after)
__global__ void k_scanMid(int* __restrict__ a, int M){
    __shared__ int ws[4];
    int t = threadIdx.x;
    int base = t*8;
    int v[8]; int tsum = 0;
    #pragma unroll
    for (int i=0;i<8;i++){ v[i] = (base+i<M)? a[base+i] : 0; tsum += v[i]; }
    int lane=t&63, w=t>>6, x=tsum;
    for (int off=1;off<64;off<<=1){ int yv=__shfl_up(x,off); if (lane>=off) x+=yv; }
    if (lane==63) ws[w]=x;
    __syncthreads();
    if (t==0){ int a2=0; for (int i=0;i<4;i++){ int tmp=ws[i]; ws[i]=a2; a2+=tmp; } }
    __syncthreads();
    int ex = x - tsum + ws[w];
    #pragma unroll
    for (int i=0;i<8;i++){ if (base+i<M) a[base+i]=ex; ex += v[i]; }
}

__global__ void k_scanAdd(int* __restrict__ out, const int* __restrict__ bsum, int M, int E){
    int base = blockIdx.x*2048 + threadIdx.x*8;
    int off = bsum[blockIdx.x];
    #pragma unroll
    for (int i=0;i<8;i++) if (base+i<M) out[base+i] += off;
    if (blockIdx.x==0 && threadIdx.x==0) out[M] = E;
}

__global__ __launch_bounds__(512) void k_scatter(const int* __restrict__ src, const int* __restrict__ dst,
                                                 int E, int NB4, int NBLK, int TS,
                                                 const int* __restrict__ csum, unsigned* __restrict__ ebuf){
    __shared__ int cur[MAXNB4];
    int t = threadIdx.x, blk = blockIdx.x;
    for (int i=t;i<NB4;i+=512) cur[i]=0;
    __syncthreads();
    int base0 = blk*SCHUNK;
    int tot = E - base0; if (tot > SCHUNK) tot = SCHUNK;
    for (int o=t;o<tot;o+=512){
        int e = base0 + o;
        int s = src[e], d = dst[e];
        int key = ((d>>7)<<2) | tile_of(s, TS);
        int r = atomicAdd(&cur[key], 1);
        ebuf[csum[key*NBLK + blk] + r] = (unsigned)s | ((unsigned)d<<16);
    }
}

// per-bucket degree count -> dinv (no global deg array)
__global__ void k_dinvB(const unsigned* __restrict__ ebuf, const int* __restrict__ csum,
                        int NBLK, float* __restrict__ dinv, int N){
    __shared__ int c[128];
    int b = blockIdx.x, t = threadIdx.x;  // 256 thr
    if (t<128) c[t]=0;
    __syncthreads();
    int e0 = csum[(4*b)*NBLK];
    int e1 = csum[(4*b+4)*NBLK];
    for (int j=e0+t;j<e1;j+=256) atomicAdd(&c[(ebuf[j]>>16)&127], 1);
    __syncthreads();
    int node = (b<<7)+t;
    if (t<128 && node<N) dinv[node] = rsqrtf((float)(c[t]+1));
}

// ---------------- GEMM1: y = (X @ W1) * dinv[row], fp16, column-swizzled ----------------
// thread tc owns cols colOf(tc,i) = (tc&15) + 64*(tc>>4) + 16*i -> stores contiguous
// 8B at half-position 8*(tc&15)+4*(tc>>4). W staged into LDS pre-permuted so the
// inner loop is unchanged.
__global__ __launch_bounds__(256) void k_gemm1(const float* __restrict__ X, const float* __restrict__ W1,
                                               const float* __restrict__ dinv, __half* __restrict__ yh, int N){
    __shared__ float Ws[128*128];
    __shared__ float Xs[32*128];
    int t = threadIdx.x;
    int row0 = blockIdx.x * 32;
    {
        float4* Wl = (float4*)Ws;
        #pragma unroll
        for (int i=0;i<16;i++){
            int f = t + i*256;          // float4 index: k = f>>5, tc = f&31
            int k = f>>5, tc = f&31;
            int c0 = (tc&15) + 64*(tc>>4);
            const float* wr = W1 + k*128 + c0;
            float4 v; v.x = wr[0]; v.y = wr[16]; v.z = wr[32]; v.w = wr[48];
            Wl[f] = v;
        }
    }
    {
        float4* Xl = (float4*)Xs;
        const float4* Xg = (const float4*)X;
        #pragma unroll
        for (int i=0;i<4;i++){
            int fi = t + i*256;
            int r = fi >> 5;
            float4 v = make_float4(0.f,0.f,0.f,0.f);
            if (row0 + r < N) v = Xg[(size_t)(row0+r)*32 + (fi & 31)];
            Xl[fi] = v;
        }
    }
    __syncthreads();
    int tc = t & 31, tr = t >> 5;
    float4 acc0={0,0,0,0}, acc1={0,0,0,0}, acc2={0,0,0,0}, acc3={0,0,0,0};
    for (int k=0;k<128;k+=4){
        float4 w0 = ld4(&Ws[(k+0)*128 + tc*4]);
        float4 w1 = ld4(&Ws[(k+1)*128 + tc*4]);
        float4 w2 = ld4(&Ws[(k+2)*128 + tc*4]);
        float4 w3 = ld4(&Ws[(k+3)*128 + tc*4]);
        #define ROWSTEP(ACC, RR) { float4 xr = ld4(&Xs[(4*tr+(RR))*128 + k]); \
            ACC.x += xr.x*w0.x + xr.y*w1.x + xr.z*w2.x + xr.w*w3.x; \
            ACC.y += xr.x*w0.y + xr.y*w1.y + xr.z*w2.y + xr.w*w3.y; \
            ACC.z += xr.x*w0.z + xr.y*w1.z + xr.z*w2.z + xr.w*w3.z; \
            ACC.w += xr.x*w0.w + xr.y*w1.w + xr.z*w2.w + xr.w*w3.w; }
        ROWSTEP(acc0,0) ROWSTEP(acc1,1) ROWSTEP(acc2,2) ROWSTEP(acc3,3)
        #undef ROWSTEP
    }
    int pbase = 8*(tc&15) + 4*(tc>>4);
    #define STORESTEP(ACC, RR) { int row = row0 + 4*tr + (RR); if (row < N){ \
        float dv = dinv[row]; \
        __half2 p0 = __floats2half2_rn(ACC.x*dv, ACC.y*dv); \
        __half2 p1 = __floats2half2_rn(ACC.z*dv, ACC.w*dv); \
        uint2 stv; stv.x = *(unsigned*)&p0; stv.y = *(unsigned*)&p1; \
        *reinterpret_cast<uint2*>(&yh[(size_t)row*128 + pbase]) = stv; } }
    STORESTEP(acc0,0) STORESTEP(acc1,1) STORESTEP(acc2,2) STORESTEP(acc3,3)
    #undef STORESTEP
}

// ---------------- layer-1 aggregation: edge-parallel, LDS fp32 accumulators ----------------
// block = one 128-node dst bucket; edges tile-ordered (soft L2 phasing).
// quarter-wave (16 lanes x 16B) per edge; 8 ds_add_f32 per lane.
__global__ __launch_bounds__(512) void k_aggL1(const __half* __restrict__ yh, const unsigned* __restrict__ ebuf,
                                               const int* __restrict__ csum, int NBLK,
                                               const float* __restrict__ dinv, const float* __restrict__ b1,
                                               __half* __restrict__ h, int N){
    __shared__ float acc[128*136];
    int t = threadIdx.x, b = blockIdx.x;
    for (int i=t;i<128*136;i+=512) acc[i]=0.f;
    int e0 = csum[(4*b)*NBLK], e1 = csum[(4*b+4)*NBLK];
    __syncthreads();
    int wv = t>>6, lane = t&63, q = lane>>4, ql = lane&15;

    #define L1BODY(UE) { \
        int s = (UE) & 0xffff, dl = ((UE)>>16)&127; \
        uint4 yv = *reinterpret_cast<const uint4*>(yh + (size_t)s*128 + ql*8); \
        float* ap = acc + dl*136 + ql; \
        __half2 h0 = *(__half2*)&yv.x, h1 = *(__half2*)&yv.y; \
        __half2 h2 = *(__half2*)&yv.z, h3 = *(__half2*)&yv.w; \
        float2 f0=__half22float2(h0), f1=__half22float2(h1); \
        float2 f2=__half22float2(h2), f3=__half22float2(h3); \
        atomicAdd(ap+0,  f0.x); atomicAdd(ap+16, f0.y); \
        atomicAdd(ap+32, f1.x); atomicAdd(ap+48, f1.y); \
        atomicAdd(ap+64, f2.x); atomicAdd(ap+80, f2.y); \
        atomicAdd(ap+96, f3.x); atomicAdd(ap+112,f3.y); }

    for (int base = e0 + wv*64; base < e1; base += 512){
        int rem = e1 - base;
        int u = (lane < rem) ? (int)ebuf[base+lane] : -1;
        if (rem >= 64){
            #pragma unroll 8
            for (int r=0;r<16;r++){
                int ue = __shfl(u, r*4+q);
                L1BODY(ue)
            }
        } else {
            for (int r=0;r<16;r++){
                int ue = __shfl(u, r*4+q);
                if (ue != -1){ L1BODY(ue) }
            }
        }
    }
    #undef L1BODY
    __syncthreads();
    // epilogue: + self-loop handled via acc? (self-loop NOT in ebuf) -> add y[node] here
    int dl = t>>2, pq = t&3;
    int node = (b<<7) + dl;
    if (node < N){
        float dv = dinv[node];
        const __half* selfp = yh + (size_t)node*128 + pq*32;
        ushort outv[32];
        #pragma unroll
        for (int m=0;m<32;m++){
            int p = pq*32 + m;
            int c = colmap1(p);
            float vv = acc[dl*136 + c] + __half2float(selfp[m]);  // self at same position
            vv = dv*vv + b1[c];
            vv = vv > 0.f ? vv : expm1f(vv);
            outv[m] = __half_as_ushort(__float2half(vv));
        }
        uint4* hp = (uint4*)(h + (size_t)node*128 + pq*32);
        hp[0] = *(uint4*)&outv[0];
        hp[1] = *(uint4*)&outv[8];
        hp[2] = *(uint4*)&outv[16];
        hp[3] = *(uint4*)&outv[24];
    }
}

// ---------------- graph boundaries ----------------
__global__ void k_bounds(const int* __restrict__ batch, int N, int* __restrict__ gstart){
    int g = threadIdx.x;
    if (g > GNUM) return;
    int lo = 0, hi = N;
    while (lo < hi){ int mid = (lo+hi)>>1; if (batch[mid] < g) lo = mid+1; else hi = mid; }
    gstart[g] = lo;
}

// ---------------- mean-pool partial sums (position-order, order-agnostic) ----------------
__global__ void k_mpoolh(const __half* __restrict__ hsrc, const int* __restrict__ gstart,
                         float* __restrict__ msum){
    int g = blockIdx.x, part = blockIdx.y, P = gridDim.y;
    int c = threadIdx.x;   // 64 threads, half2 positions
    int s0 = gstart[g], s1 = gstart[g+1];
    int len = s1 - s0;
    int per = (len + P - 1) / P;
    int rbeg = s0 + part*per, rend = rbeg + per; if (rend > s1) rend = s1;
    float sx = 0.f, sy = 0.f;
    const __half2* h2 = (const __half2*)hsrc;
    for (int r = rbeg; r < rend; ++r){
        float2 f = __half22float2(h2[(size_t)r*64 + c]);
        sx += f.x; sy += f.y;
    }
    if (rend > rbeg){
        atomicAdd(&msum[g*128 + 2*c], sx);
        atomicAdd(&msum[g*128 + 2*c+1], sy);
    }
}

__global__ void k_mpool(const float* __restrict__ srcm, const int* __restrict__ gstart,
                        float* __restrict__ msum, int C){
    int g = blockIdx.x, part = blockIdx.y, P = gridDim.y;
    int c = threadIdx.x;
    if (c >= C) return;
    int s0 = gstart[g], s1 = gstart[g+1];
    int len = s1 - s0;
    int per = (len + P - 1) / P;
    int rbeg = s0 + part*per, rend = rbeg + per; if (rend > s1) rend = s1;
    float sum = 0.f;
    for (int r = rbeg; r < rend; ++r) sum += srcm[(size_t)r*C + c];
    if (rend > rbeg) atomicAdd(&msum[g*C + c], sum);
}

__global__ void k_mlp1(const float* __restrict__ msum, const int* __restrict__ gstart,
                       const float* __restrict__ mW1, const float* __restrict__ mb1,
                       float* __restrict__ r1){
    int g = blockIdx.x, c = threadIdx.x;   // 128
    int cnt = gstart[g+1] - gstart[g];
    float inv = 1.f / (float)(cnt > 1 ? cnt : 1);
    float a = mb1[c];
    for (int p=0;p<128;p++)
        a = fmaf(msum[g*128+p]*inv, mW1[colmap1(p)*128 + c], a);
    r1[g*128 + pos1(c)] = fmaxf(a, 0.f);   // store position-order for gemm2
}

__global__ void k_mlp2(const float* __restrict__ msum2, const int* __restrict__ gstart,
                       const float* __restrict__ mW2, const float* __restrict__ mb2,
                       float* __restrict__ r2){
    int g = blockIdx.x, c = threadIdx.x;
    if (c >= 32) return;
    int cnt = gstart[g+1] - gstart[g];
    float inv = 1.f / (float)(cnt > 1 ? cnt : 1);
    float a = mb2[c];
    for (int p=0;p<32;p++)
        a = fmaf(msum2[g*32+p]*inv, mW2[colmap2(p)*32 + c], a);
    r2[g*32 + pos2(c)] = fmaxf(a, 0.f);
}

// ---------------- GEMM2: y2 = ((h + r1[batch]) @ W2) * dinv, fp16 swizzled ----------------
__global__ __launch_bounds__(256) void k_gemm2(const __half* __restrict__ h, const float* __restrict__ vn,
                                               const int* __restrict__ batch, const float* __restrict__ W2,
                                               const float* __restrict__ dinv, __half* __restrict__ y2, int N){
    __shared__ float W2s[128*32];   // [input-pos][out-col grouped]
    int t = threadIdx.x;
    for (int f = t; f < 1024; f += 256){
        int p = f>>3, j = f&7;
        const float* wr = W2 + colmap1(p)*32 + j;
        float4 v; v.x = wr[0]; v.y = wr[8]; v.z = wr[16]; v.w = wr[24];
        ((float4*)W2s)[f] = v;
    }
    __syncthreads();
    int row0 = blockIdx.x*64;
    int tc = t & 7, trg = t >> 3;
    int ra = row0 + 2*trg, rb = ra + 1;
    bool oka = ra < N, okb = rb < N;
    const __half* hpa = h + (size_t)(oka ? ra : 0)*128;
    const __half* hpb = h + (size_t)(okb ? rb : 0)*128;
    const float* vpa = vn + (size_t)(oka ? batch[ra] : 0)*128;
    const float* vpb = vn + (size_t)(okb ? batch[rb] : 0)*128;
    float4 acca={0,0,0,0}, accb={0,0,0,0};
    for (int k=0;k<128;k+=4){
        float4 w0 = ld4(&W2s[(k+0)*32 + tc*4]);
        float4 w1 = ld4(&W2s[(k+1)*32 + tc*4]);
        float4 w2 = ld4(&W2s[(k+2)*32 + tc*4]);
        float4 w3 = ld4(&W2s[(k+3)*32 + tc*4]);
        {
            uint2 u = *reinterpret_cast<const uint2*>(&hpa[k]);
            __half2 h0 = *(__half2*)&u.x, h1 = *(__half2*)&u.y;
            float2 f0 = __half22float2(h0), f1 = __half22float2(h1);
            float4 bb = ld4(vpa + k);
            float ax=f0.x+bb.x, ay=f0.y+bb.y, az=f1.x+bb.z, aw=f1.y+bb.w;
            acca.x += ax*w0.x + ay*w1.x + az*w2.x + aw*w3.x;
            acca.y += ax*w0.y + ay*w1.y + az*w2.y + aw*w3.y;
            acca.z += ax*w0.z + ay*w1.z + az*w2.z + aw*w3.z;
            acca.w += ax*w0.w + ay*w1.w + az*w2.w + aw*w3.w;
        }
        {
            uint2 u = *reinterpret_cast<const uint2*>(&hpb[k]);
            __half2 h0 = *(__half2*)&u.x, h1 = *(__half2*)&u.y;
            float2 f0 = __half22float2(h0), f1 = __half22float2(h1);
            float4 bb = ld4(vpb + k);
            float ax=f0.x+bb.x, ay=f0.y+bb.y, az=f1.x+bb.z, aw=f1.y+bb.w;
            accb.x += ax*w0.x + ay*w1.x + az*w2.x + aw*w3.x;
            accb.y += ax*w0.y + ay*w1.y + az*w2.y + aw*w3.y;
            accb.z += ax*w0.z + ay*w1.z + az*w2.z + aw*w3.z;
            accb.w += ax*w0.w + ay*w1.w + az*w2.w + aw*w3.w;
        }
    }
    if (oka){
        float dv = dinv[ra];
        __half2 p0 = __floats2half2_rn(acca.x*dv, acca.y*dv);
        __half2 p1 = __floats2half2_rn(acca.z*dv, acca.w*dv);
        uint2 stv; stv.x = *(unsigned*)&p0; stv.y = *(unsigned*)&p1;
        *reinterpret_cast<uint2*>(&y2[(size_t)ra*32 + tc*4]) = stv;
    }
    if (okb){
        float dv = dinv[rb];
        __half2 p0 = __floats2half2_rn(accb.x*dv, accb.y*dv);
        __half2 p1 = __floats2half2_rn(accb.z*dv, accb.w*dv);
        uint2 stv; stv.x = *(unsigned*)&p0; stv.y = *(unsigned*)&p1;
        *reinterpret_cast<uint2*>(&y2[(size_t)rb*32 + tc*4]) = stv;
    }
}

// ---------------- layer-2 aggregation: edge-parallel LDS (octet-wave) ----------------
__global__ __launch_bounds__(512) void k_aggL2(const __half* __restrict__ y2, const unsigned* __restrict__ ebuf,
                                               const int* __restrict__ csum, int NBLK,
                                               const float* __restrict__ dinv, const float* __restrict__ b2,
                                               float* __restrict__ Zpre, int N){
    __shared__ float acc[128*33];
    int t = threadIdx.x, b = blockIdx.x;
    for (int i=t;i<128*33;i+=512) acc[i]=0.f;
    int e0 = csum[(4*b)*NBLK], e1 = csum[(4*b+4)*NBLK];
    __syncthreads();
    int wv = t>>6, lane = t&63, o = lane>>3, ol = lane&7;

    #define L2BODY(UE) { \
        int s = (UE) & 0xffff, dl = ((UE)>>16)&127; \
        uint2 yv = *reinterpret_cast<const uint2*>(y2 + (size_t)s*32 + ol*4); \
        float* ap = acc + dl*33 + ol; \
        __half2 h0 = *(__half2*)&yv.x, h1 = *(__half2*)&yv.y; \
        float2 f0=__half22float2(h0), f1=__half22float2(h1); \
        atomicAdd(ap+0,  f0.x); atomicAdd(ap+8,  f0.y); \
        atomicAdd(ap+16, f1.x); atomicAdd(ap+24, f1.y); }

    for (int base = e0 + wv*64; base < e1; base += 512){
        int rem = e1 - base;
        int u = (lane < rem) ? (int)ebuf[base+lane] : -1;
        if (rem >= 64){
            #pragma unroll
            for (int r=0;r<8;r++){
                int ue = __shfl(u, r*8+o);
                L2BODY(ue)
            }
        } else {
            for (int r=0;r<8;r++){
                int ue = __shfl(u, r*8+o);
                if (ue != -1){ L2BODY(ue) }
            }
        }
    }
    #undef L2BODY
    __syncthreads();
    int dl = t>>2, pq = t&3;
    int node = (b<<7) + dl;
    if (node < N){
        float dv = dinv[node];
        const __half* selfp = y2 + (size_t)node*32 + pq*8;
        float ov[8];
        #pragma unroll
        for (int m=0;m<8;m++){
            int p = pq*8 + m;
            int c = colmap2(p);
            ov[m] = dv*(acc[dl*33 + c] + __half2float(selfp[m])) + b2[c];
        }
        float4* zp = (float4*)(Zpre + (size_t)node*32 + pq*8);
        zp[0] = *(float4*)&ov[0];
        zp[1] = *(float4*)&ov[4];
    }
}

// ---------------- + virtual node + softmax (unswizzle on final store) ----------------
__global__ void k_softmax(const float* __restrict__ Zpre, const float* __restrict__ r2,
                          const int* __restrict__ batch, float* __restrict__ Zout, int N){
    int r = blockIdx.x*8 + (threadIdx.x>>5);
    int p = threadIdx.x & 31;
    if (r >= N) return;
    float z = Zpre[(size_t)r*32+p] + r2[batch[r]*32 + p];
    float m = z;
    #pragma unroll
    for (int off=16; off>=1; off>>=1) m = fmaxf(m, __shfl_xor(m, off));
    float e = expf(z - m);
    float s = e;
    #pragma unroll
    for (int off=16; off>=1; off>>=1) s += __shfl_xor(s, off);
    Zout[(size_t)r*32 + colmap2(p)] = e / s;
}

extern "C" void kernel_launch(void* const* d_in, const int* in_sizes, int n_in,
                              void* d_out, int out_size, void* d_ws, size_t ws_size,
                              hipStream_t stream){
    const float* X   = (const float*)d_in[0];
    const float* W1  = (const float*)d_in[1];
    const float* b1  = (const float*)d_in[2];
    const float* W2  = (const float*)d_in[3];
    const float* b2  = (const float*)d_in[4];
    const float* mW1 = (const float*)d_in[5];
    const float* mb1 = (const float*)d_in[6];
    const float* mW2 = (const float*)d_in[7];
    const float* mb2 = (const float*)d_in[8];
    const int*   ei  = (const int*)d_in[9];
    const int*   batch = (const int*)d_in[10];
    int N = in_sizes[0] / 128;
    int E = in_sizes[9] / 2;
    const int* src = ei;
    const int* dst = ei + E;
    float* Zout = (float*)d_out;

    int NB   = (N + 127) >> 7;          // 391
    int NB4  = NB * 4;                  // 1564 (<= MAXNB4)
    int NBLK = (E + SCHUNK - 1)/SCHUNK; // 98
    int M    = NB4 * NBLK;              // ~153K
    int SA   = (M + 2047)/2048;         // 75 (<= 2048)
    int TS   = (N + 3)/4;               // 12500

    char* wsp = (char*)d_ws;
    size_t off = 0;
    auto alloc = [&](size_t bytes)->char*{
        char* p = wsp + off; off += (bytes + 255) & ~(size_t)255; return p;
    };
    // zero zone (single small memset)
    float* msum  = (float*)alloc((size_t)GNUM*128*4);
    float* msum2 = (float*)alloc((size_t)GNUM*32*4);
    size_t zero_bytes = off;
    // rest
    int*   cntg  = (int*)  alloc((size_t)M*4);
    int*   csum  = (int*)  alloc((size_t)(M+1)*4);
    int*   bsumA = (int*)  alloc((size_t)SA*4);
    int*   gstart= (int*)  alloc((GNUM+1)*4);
    unsigned* ebuf = (unsigned*)alloc((size_t)E*4);
    float* dinvp = (float*)alloc((size_t)N*4);
    __half* yh   = (__half*)alloc((size_t)N*128*2);
    __half* h    = (__half*)alloc((size_t)N*128*2);
    __half* y2h  = (__half*)alloc((size_t)N*32*2);
    float* Zpre  = (float*)alloc((size_t)N*32*4);
    float* r1buf = (float*)alloc((size_t)GNUM*128*4);
    float* r2buf = (float*)alloc((size_t)GNUM*32*4);
    (void)ws_size; (void)n_in; (void)out_size;

    hipMemsetAsync(d_ws, 0, zero_bytes, stream);

    k_hist   <<<NBLK, 512, 0, stream>>>(src, dst, E, NB4, NBLK, TS, cntg);
    k_scanA  <<<SA, 256, 0, stream>>>(cntg, csum, bsumA, M);
    k_scanMid<<<1, 256, 0, stream>>>(bsumA, SA);
    k_scanAdd<<<SA, 256, 0, stream>>>(csum, bsumA, M, E);
    k_scatter<<<NBLK, 512, 0, stream>>>(src, dst, E, NB4, NBLK, TS, csum, ebuf);
    k_dinvB  <<<NB, 256, 0, stream>>>(ebuf, csum, NBLK, dinvp, N);

    k_gemm1  <<<(N+31)/32, 256, 0, stream>>>(X, W1, dinvp, yh, N);
    k_aggL1  <<<NB, 512, 0, stream>>>(yh, ebuf, csum, NBLK, dinvp, b1, h, N);

    k_bounds <<<1, 128, 0, stream>>>(batch, N, gstart);
    k_mpoolh <<<dim3(GNUM,8), 64, 0, stream>>>(h, gstart, msum);
    k_mlp1   <<<GNUM, 128, 0, stream>>>(msum, gstart, mW1, mb1, r1buf);

    k_gemm2  <<<(N+63)/64, 256, 0, stream>>>(h, r1buf, batch, W2, dinvp, y2h, N);
    k_aggL2  <<<NB, 512, 0, stream>>>(y2h, ebuf, csum, NBLK, dinvp, b2, Zpre, N);

    k_mpool  <<<dim3(GNUM,8), 64, 0, stream>>>(Zpre, gstart, msum2, 32);
    k_mlp2   <<<GNUM, 64, 0, stream>>>(msum2, gstart, mW2, mb2, r2buf);
    k_softmax<<<(N+7)/8, 256, 0, stream>>>(Zpre, r2buf, batch, Zout, N);
}

// Round 5
// 272.559 us; speedup vs baseline: 7.0623x; 7.0623x over previous
//
#include <hip/hip_runtime.h>
#include <hip/hip_bf16.h>
#include <hip/hip_fp16.h>

#define DEV_INLINE __device__ __forceinline__

static DEV_INLINE float4 ld4(const float* p){ return *reinterpret_cast<const float4*>(p); }
static DEV_INLINE void st4(float* p, float4 v){ *reinterpret_cast<float4*>(p) = v; }

#define GNUM 64
#define CHUNK 4096
#define MAXNB 1024   // bucket = dst>>7; N <= 65536 (u16 packing)

// ======================= bucketed CSR build (round-2, proven) =======================
__global__ __launch_bounds__(256) void k_bucket_hist(const int* __restrict__ dst, int E, int NB,
                                                     int* __restrict__ bcnt){
    __shared__ int cnt[MAXNB];
    int t = threadIdx.x; int base0 = blockIdx.x*CHUNK;
    for (int i=t;i<NB;i+=256) cnt[i]=0;
    __syncthreads();
    int tot = E - base0; if (tot > CHUNK) tot = CHUNK;
    #pragma unroll
    for (int k=0;k<16;k++){
        int o = t + k*256;
        if (o < tot) atomicAdd(&cnt[dst[base0+o]>>7], 1);
    }
    __syncthreads();
    for (int i=t;i<NB;i+=256) if (cnt[i]) atomicAdd(&bcnt[i], cnt[i]);
}

// one-block exclusive scan, M <= 1024; writes out[M]=total if total>=0
__global__ void k_scan1b(const int* __restrict__ in, int* __restrict__ out, int M, int total){
    __shared__ int ws[4];
    int t = threadIdx.x;
    int i0 = t*4;
    int c0=(i0+0<M)?in[i0+0]:0, c1=(i0+1<M)?in[i0+1]:0;
    int c2=(i0+2<M)?in[i0+2]:0, c3=(i0+3<M)?in[i0+3]:0;
    int tsum=c0+c1+c2+c3;
    int lane=t&63, w=t>>6;
    int x=tsum;
    for (int off=1;off<64;off<<=1){ int yv=__shfl_up(x,off); if (lane>=off) x+=yv; }
    if (lane==63) ws[w]=x;
    __syncthreads();
    if (t==0){ int a=0; for (int i=0;i<4;i++){ int tmp=ws[i]; ws[i]=a; a+=tmp; } }
    __syncthreads();
    int ex = x - tsum + ws[w];
    if (i0+0<M) out[i0+0]=ex; ex+=c0;
    if (i0+1<M) out[i0+1]=ex; ex+=c1;
    if (i0+2<M) out[i0+2]=ex; ex+=c2;
    if (i0+3<M) out[i0+3]=ex;
    if (t==0 && total>=0) out[M]=total;
}

__global__ __launch_bounds__(256) void k_bucket_scatter(const int* __restrict__ src, const int* __restrict__ dst,
                                                        int E, int NB, const int* __restrict__ bbase,
                                                        int* __restrict__ bfill, unsigned* __restrict__ ebuf){
    __shared__ int cnt[MAXNB];
    __shared__ int pfx[MAXNB];
    __shared__ int gbase[MAXNB];
    __shared__ unsigned stage[CHUNK];
    __shared__ int ws[4];
    int t = threadIdx.x; int base0 = blockIdx.x*CHUNK;
    int tot = E - base0; if (tot > CHUNK) tot = CHUNK;
    for (int i=t;i<NB;i+=256) cnt[i]=0;
    __syncthreads();
    unsigned v[16]; int rk[16];
    #pragma unroll
    for (int k=0;k<16;k++){
        int o = t + k*256;
        if (o < tot){
            int e = base0 + o;
            int s = src[e], d = dst[e];
            v[k] = (unsigned)s | ((unsigned)d<<16);
            rk[k] = atomicAdd(&cnt[d>>7], 1);
        } else { v[k]=0u; rk[k]=-1; }
    }
    __syncthreads();
    int i0 = t*4;
    int c0=(i0+0<NB)?cnt[i0+0]:0, c1=(i0+1<NB)?cnt[i0+1]:0;
    int c2=(i0+2<NB)?cnt[i0+2]:0, c3=(i0+3<NB)?cnt[i0+3]:0;
    int tsum=c0+c1+c2+c3;
    int lane=t&63, w=t>>6;
    int x=tsum;
    for (int off=1;off<64;off<<=1){ int yv=__shfl_up(x,off); if (lane>=off) x+=yv; }
    if (lane==63) ws[w]=x;
    __syncthreads();
    if (t==0){ int a=0; for (int i=0;i<4;i++){ int tmp=ws[i]; ws[i]=a; a+=tmp; } }
    __syncthreads();
    int ex = x - tsum + ws[w];
    if (i0+0<NB) pfx[i0+0]=ex; ex+=c0;
    if (i0+1<NB) pfx[i0+1]=ex; ex+=c1;
    if (i0+2<NB) pfx[i0+2]=ex; ex+=c2;
    if (i0+3<NB) pfx[i0+3]=ex;
    __syncthreads();
    for (int i=t;i<NB;i+=256){
        int c = cnt[i];
        gbase[i] = c ? (bbase[i] + atomicAdd(&bfill[i], c)) : 0;
    }
    __syncthreads();
    #pragma unroll
    for (int k=0;k<16;k++) if (rk[k]>=0){ int b = (int)(v[k]>>23); stage[pfx[b]+rk[k]] = v[k]; }
    __syncthreads();
    for (int j=t;j<tot;j+=256){
        unsigned u = stage[j];
        int b = (int)(u>>23);
        ebuf[gbase[b] + (j - pfx[b])] = u;
    }
}

__global__ void k_bucket_deg(const unsigned* __restrict__ ebuf, const int* __restrict__ bbase,
                             int* __restrict__ deg, int N){
    __shared__ int c2[128];
    int b = blockIdx.x, t = threadIdx.x;
    if (t<128) c2[t]=0;
    __syncthreads();
    int s0=bbase[b], s1=bbase[b+1];
    for (int j=s0+t; j<s1; j+=256){
        unsigned u = ebuf[j];
        atomicAdd(&c2[(u>>16)&127], 1);
    }
    __syncthreads();
    int node = (b<<7)+t;
    if (t<128 && node<N) deg[node]=c2[t];
}

__global__ void k_bucket_fill(const unsigned* __restrict__ ebuf, const int* __restrict__ bbase,
                              const int* __restrict__ rs, int* __restrict__ csr, int N){
    __shared__ int rsl[128]; __shared__ int cur[128];
    int b = blockIdx.x, t = threadIdx.x;
    int node = (b<<7)+t;
    if (t<128){ cur[t]=0; rsl[t] = (node<N)? rs[node] : 0; }
    __syncthreads();
    int s0=bbase[b], s1=bbase[b+1];
    for (int j=s0+t; j<s1; j+=256){
        unsigned u = ebuf[j];
        int ld = (u>>16)&127;
        int p = atomicAdd(&cur[ld], 1);
        csr[rsl[ld]+p] = (int)(u & 0xffffu);
    }
}

__global__ void k_dinv(const int* __restrict__ deg, float* __restrict__ dinv, int N){
    int i = blockIdx.x*256 + threadIdx.x;
    if (i < N) dinv[i] = rsqrtf((float)(deg[i] + 1));
}

// scan of deg over N
__global__ void k_scan_blocks(const int* __restrict__ deg, int* __restrict__ rs,
                              int* __restrict__ bsum, int N){
    __shared__ int ws[4];
    int t = threadIdx.x;
    int base = blockIdx.x*1024 + t*4;
    int v0 = (base+0<N)? deg[base+0]:0;
    int v1 = (base+1<N)? deg[base+1]:0;
    int v2 = (base+2<N)? deg[base+2]:0;
    int v3 = (base+3<N)? deg[base+3]:0;
    int tsum = v0+v1+v2+v3;
    int lane = t & 63, w = t >> 6;
    int x = tsum;
    for (int off=1; off<64; off<<=1){
        int yv = __shfl_up(x, off);
        if (lane >= off) x += yv;
    }
    if (lane == 63) ws[w] = x;
    __syncthreads();
    if (t == 0){
        int a = 0;
        for (int i=0;i<4;i++){ int tmp=ws[i]; ws[i]=a; a+=tmp; }
    }
    __syncthreads();
    int ex = x - tsum + ws[w];
    if (base+0<N) rs[base+0] = ex; ex += v0;
    if (base+1<N) rs[base+1] = ex; ex += v1;
    if (base+2<N) rs[base+2] = ex; ex += v2;
    if (base+3<N) rs[base+3] = ex;
    if (t == 255) bsum[blockIdx.x] = ws[3] + x;
}

__global__ void k_scan_mid(int* __restrict__ bsum, int B){  // B <= 64
    int lane = threadIdx.x;
    int v = (lane < B)? bsum[lane] : 0;
    int x = v;
    for (int off=1; off<64; off<<=1){
        int yv = __shfl_up(x, off);
        if (lane >= off) x += yv;
    }
    if (lane < B) bsum[lane] = x - v;
}

__global__ void k_scan_add(int* __restrict__ rs, const int* __restrict__ bsum, int N, int E){
    int base = blockIdx.x*1024 + threadIdx.x*4;
    int off = bsum[blockIdx.x];
    #pragma unroll
    for (int j=0;j<4;j++) if (base+j < N) rs[base+j] += off;
    if (blockIdx.x==0 && threadIdx.x==0) rs[N] = E;
}

// ---------------- GEMM1: y = (X @ W1) * dinv[row], fp16 out; writes zero row N ----------------
__global__ __launch_bounds__(256) void k_gemm1(const float* __restrict__ X, const float* __restrict__ W1,
                                               const float* __restrict__ dinv, __half* __restrict__ yh, int N){
    __shared__ float Ws[128*128];
    __shared__ float Xs[32*128];
    int t = threadIdx.x;
    int row0 = blockIdx.x * 32;
    if (blockIdx.x==0 && t < 32)
        reinterpret_cast<uint2*>(yh + (size_t)N*128)[t] = make_uint2(0u,0u);
    {
        const float4* Wg = (const float4*)W1;
        float4* Wl = (float4*)Ws;
        #pragma unroll
        for (int i=0;i<16;i++) Wl[t + i*256] = Wg[t + i*256];
    }
    {
        float4* Xl = (float4*)Xs;
        const float4* Xg = (const float4*)X;
        #pragma unroll
        for (int i=0;i<4;i++){
            int fi = t + i*256;
            int r = fi >> 5;
            float4 v = make_float4(0.f,0.f,0.f,0.f);
            if (row0 + r < N) v = Xg[(size_t)(row0+r)*32 + (fi & 31)];
            Xl[fi] = v;
        }
    }
    __syncthreads();
    int tc = t & 31, tr = t >> 5;
    float4 acc0={0,0,0,0}, acc1={0,0,0,0}, acc2={0,0,0,0}, acc3={0,0,0,0};
    for (int k=0;k<128;k+=4){
        float4 w0 = ld4(&Ws[(k+0)*128 + tc*4]);
        float4 w1 = ld4(&Ws[(k+1)*128 + tc*4]);
        float4 w2 = ld4(&Ws[(k+2)*128 + tc*4]);
        float4 w3 = ld4(&Ws[(k+3)*128 + tc*4]);
        #define ROWSTEP(ACC, RR) { float4 xr = ld4(&Xs[(4*tr+(RR))*128 + k]); \
            ACC.x += xr.x*w0.x + xr.y*w1.x + xr.z*w2.x + xr.w*w3.x; \
            ACC.y += xr.x*w0.y + xr.y*w1.y + xr.z*w2.y + xr.w*w3.y; \
            ACC.z += xr.x*w0.z + xr.y*w1.z + xr.z*w2.z + xr.w*w3.z; \
            ACC.w += xr.x*w0.w + xr.y*w1.w + xr.z*w2.w + xr.w*w3.w; }
        ROWSTEP(acc0,0) ROWSTEP(acc1,1) ROWSTEP(acc2,2) ROWSTEP(acc3,3)
        #undef ROWSTEP
    }
    #define STORESTEP(ACC, RR) { int row = row0 + 4*tr + (RR); if (row < N){ \
        float dv = dinv[row]; \
        __half2 p0 = __floats2half2_rn(ACC.x*dv, ACC.y*dv); \
        __half2 p1 = __floats2half2_rn(ACC.z*dv, ACC.w*dv); \
        uint2 stv; stv.x = *(unsigned*)&p0; stv.y = *(unsigned*)&p1; \
        *reinterpret_cast<uint2*>(&yh[(size_t)row*128 + tc*4]) = stv; } }
    STORESTEP(acc0,0) STORESTEP(acc1,1) STORESTEP(acc2,2) STORESTEP(acc3,3)
    #undef STORESTEP
}

// ---------------- layer-1 aggregation: wave/node, zero-row trick, fp16 pair accum, 4x ILP ----------------
__global__ void k_agg1(const __half* __restrict__ yh, const float* __restrict__ dinv,
                       const float* __restrict__ b1, const int* __restrict__ rs,
                       const int* __restrict__ csr, __half* __restrict__ h, int N){
    int wid = (int)((blockIdx.x * blockDim.x + threadIdx.x) >> 6);
    if (wid >= N) return;
    int lane = threadIdx.x & 63;
    int half = lane >> 5, hl = lane & 31;
    int beg = rs[wid], end = rs[wid+1];
    int len = end - beg;
    int len0 = (len + 1) >> 1;
    int hbeg = beg + (half ? len0 : 0);
    int hlen = half ? (len - len0) : len0;
    const __half* ybase = yh + hl*4;   // this lane's 8B column slice
    float4 acc = make_float4(0.f,0.f,0.f,0.f);
    if (half == 0){   // self loop once
        uint2 u = *reinterpret_cast<const uint2*>(ybase + (size_t)wid*128);
        float2 f0 = __half22float2(*(__half2*)&u.x), f1 = __half22float2(*(__half2*)&u.y);
        acc.x=f0.x; acc.y=f0.y; acc.z=f1.x; acc.w=f1.y;
    }
    int iters = (len0 + 31) >> 5;
    for (int c=0;c<iters;c++){
        int o = c*32 + hl;
        int idx = (o < hlen) ? csr[hbeg + o] : N;   // N = zero row
        int tmax = len0 - c*32; if (tmax > 32) tmax = 32;  // wave-uniform bound
        __half2 a0 = __float2half2_rn(0.f), a1 = __float2half2_rn(0.f);
        int tt = 0;
        for (; tt+4 <= tmax; tt += 4){
            int s0 = __shfl(idx, (half<<5)+tt+0);
            int s1 = __shfl(idx, (half<<5)+tt+1);
            int s2 = __shfl(idx, (half<<5)+tt+2);
            int s3 = __shfl(idx, (half<<5)+tt+3);
            uint2 u0 = *reinterpret_cast<const uint2*>(ybase + (size_t)s0*128);
            uint2 u1 = *reinterpret_cast<const uint2*>(ybase + (size_t)s1*128);
            uint2 u2 = *reinterpret_cast<const uint2*>(ybase + (size_t)s2*128);
            uint2 u3 = *reinterpret_cast<const uint2*>(ybase + (size_t)s3*128);
            a0 = __hadd2(a0, *(__half2*)&u0.x); a1 = __hadd2(a1, *(__half2*)&u0.y);
            a0 = __hadd2(a0, *(__half2*)&u1.x); a1 = __hadd2(a1, *(__half2*)&u1.y);
            a0 = __hadd2(a0, *(__half2*)&u2.x); a1 = __hadd2(a1, *(__half2*)&u2.y);
            a0 = __hadd2(a0, *(__half2*)&u3.x); a1 = __hadd2(a1, *(__half2*)&u3.y);
        }
        for (; tt < tmax; ++tt){
            int s = __shfl(idx, (half<<5)+tt);
            uint2 u = *reinterpret_cast<const uint2*>(ybase + (size_t)s*128);
            a0 = __hadd2(a0, *(__half2*)&u.x); a1 = __hadd2(a1, *(__half2*)&u.y);
        }
        float2 f0 = __half22float2(a0), f1 = __half22float2(a1);
        acc.x += f0.x; acc.y += f0.y; acc.z += f1.x; acc.w += f1.y;
    }
    acc.x += __shfl_xor(acc.x, 32);
    acc.y += __shfl_xor(acc.y, 32);
    acc.z += __shfl_xor(acc.z, 32);
    acc.w += __shfl_xor(acc.w, 32);
    if (half == 0){
        float dv = dinv[wid];
        float4 bb = ld4(&b1[hl*4]);
        float4 o;
        o.x = dv*acc.x + bb.x; o.y = dv*acc.y + bb.y;
        o.z = dv*acc.z + bb.z; o.w = dv*acc.w + bb.w;
        o.x = o.x > 0.f ? o.x : expm1f(o.x);
        o.y = o.y > 0.f ? o.y : expm1f(o.y);
        o.z = o.z > 0.f ? o.z : expm1f(o.z);
        o.w = o.w > 0.f ? o.w : expm1f(o.w);
        __half2 p0 = __floats2half2_rn(o.x, o.y);
        __half2 p1 = __floats2half2_rn(o.z, o.w);
        uint2 stv; stv.x = *(unsigned*)&p0; stv.y = *(unsigned*)&p1;
        *reinterpret_cast<uint2*>(&h[(size_t)wid*128 + hl*4]) = stv;
    }
}

// ---------------- graph boundaries ----------------
__global__ void k_bounds(const int* __restrict__ batch, int N, int* __restrict__ gstart){
    int g = threadIdx.x;
    if (g > GNUM) return;
    int lo = 0, hi = N;
    while (lo < hi){ int mid = (lo+hi)>>1; if (batch[mid] < g) lo = mid+1; else hi = mid; }
    gstart[g] = lo;
}

// ---------------- mean-pool partial sums ----------------
__global__ void k_mpoolh(const __half* __restrict__ hsrc, const int* __restrict__ gstart,
                         float* __restrict__ msum){
    int g = blockIdx.x, part = blockIdx.y, P = gridDim.y;
    int c = threadIdx.x;   // 64 threads, half2 cols
    int s0 = gstart[g], s1 = gstart[g+1];
    int len = s1 - s0;
    int per = (len + P - 1) / P;
    int rbeg = s0 + part*per, rend = rbeg + per; if (rend > s1) rend = s1;
    float sx = 0.f, sy = 0.f;
    const __half2* h2 = (const __half2*)hsrc;
    for (int r = rbeg; r < rend; ++r){
        float2 f = __half22float2(h2[(size_t)r*64 + c]);
        sx += f.x; sy += f.y;
    }
    if (rend > rbeg){
        atomicAdd(&msum[g*128 + 2*c], sx);
        atomicAdd(&msum[g*128 + 2*c+1], sy);
    }
}

__global__ void k_mpool(const float* __restrict__ srcm, const int* __restrict__ gstart,
                        float* __restrict__ msum, int C){
    int g = blockIdx.x, part = blockIdx.y, P = gridDim.y;
    int c = threadIdx.x;
    if (c >= C) return;
    int s0 = gstart[g], s1 = gstart[g+1];
    int len = s1 - s0;
    int per = (len + P - 1) / P;
    int rbeg = s0 + part*per, rend = rbeg + per; if (rend > s1) rend = s1;
    float sum = 0.f;
    for (int r = rbeg; r < rend; ++r) sum += srcm[(size_t)r*C + c];
    if (rend > rbeg) atomicAdd(&msum[g*C + c], sum);
}

__global__ void k_mlp1(const float* __restrict__ msum, const int* __restrict__ gstart,
                       const float* __restrict__ mW1, const float* __restrict__ mb1,
                       float* __restrict__ r1){
    int g = blockIdx.x, c = threadIdx.x;   // 128 threads
    int cnt = gstart[g+1] - gstart[g];
    float inv = 1.f / (float)(cnt > 1 ? cnt : 1);
    float acc = mb1[c];
    for (int k=0;k<128;k++) acc = fmaf(msum[g*128+k]*inv, mW1[k*128+c], acc);
    r1[g*128+c] = fmaxf(acc, 0.f);
}

__global__ void k_mlp2(const float* __restrict__ msum2, const int* __restrict__ gstart,
                       const float* __restrict__ mW2, const float* __restrict__ mb2,
                       float* __restrict__ r2){
    int g = blockIdx.x, c = threadIdx.x;
    if (c >= 32) return;
    int cnt = gstart[g+1] - gstart[g];
    float inv = 1.f / (float)(cnt > 1 ? cnt : 1);
    float acc = mb2[c];
    for (int k=0;k<32;k++) acc = fmaf(msum2[g*32+k]*inv, mW2[k*32+c], acc);
    r2[g*32+c] = fmaxf(acc, 0.f);
}

// ---------------- GEMM2: y2 = ((h + r1[batch]) @ W2) * dinv, fp16 h in / fp16 out ----------------
__global__ __launch_bounds__(256) void k_gemm2(const __half* __restrict__ h, const float* __restrict__ vn,
                                               const int* __restrict__ batch, const float* __restrict__ W2,
                                               const float* __restrict__ dinv, __half* __restrict__ y2, int N){
    __shared__ float W2s[128*32];
    int t = threadIdx.x;
    if (blockIdx.x==0 && t < 8)
        reinterpret_cast<uint2*>(y2 + (size_t)N*32)[t] = make_uint2(0u,0u);
    {
        float4* Wl = (float4*)W2s;
        const float4* Wg = (const float4*)W2;
        #pragma unroll
        for (int i=0;i<4;i++) Wl[t + i*256] = Wg[t + i*256];
    }
    __syncthreads();
    int row0 = blockIdx.x*64;
    int tc = t & 7, trg = t >> 3;
    int ra = row0 + 2*trg, rb = ra + 1;
    bool oka = ra < N, okb = rb < N;
    const __half* hpa = h + (size_t)(oka ? ra : 0)*128;
    const __half* hpb = h + (size_t)(okb ? rb : 0)*128;
    const float* vpa = vn + (size_t)(oka ? batch[ra] : 0)*128;
    const float* vpb = vn + (size_t)(okb ? batch[rb] : 0)*128;
    float4 acca={0,0,0,0}, accb={0,0,0,0};
    for (int k=0;k<128;k+=4){
        float4 w0 = ld4(&W2s[(k+0)*32 + tc*4]);
        float4 w1 = ld4(&W2s[(k+1)*32 + tc*4]);
        float4 w2 = ld4(&W2s[(k+2)*32 + tc*4]);
        float4 w3 = ld4(&W2s[(k+3)*32 + tc*4]);
        {
            uint2 u = *reinterpret_cast<const uint2*>(&hpa[k]);
            float2 f0 = __half22float2(*(__half2*)&u.x), f1 = __half22float2(*(__half2*)&u.y);
            float4 bb = ld4(vpa + k);
            float ax=f0.x+bb.x, ay=f0.y+bb.y, az=f1.x+bb.z, aw=f1.y+bb.w;
            acca.x += ax*w0.x + ay*w1.x + az*w2.x + aw*w3.x;
            acca.y += ax*w0.y + ay*w1.y + az*w2.y + aw*w3.y;
            acca.z += ax*w0.z + ay*w1.z + az*w2.z + aw*w3.z;
            acca.w += ax*w0.w + ay*w1.w + az*w2.w + aw*w3.w;
        }
        {
            uint2 u = *reinterpret_cast<const uint2*>(&hpb[k]);
            float2 f0 = __half22float2(*(__half2*)&u.x), f1 = __half22float2(*(__half2*)&u.y);
            float4 bb = ld4(vpb + k);
            float ax=f0.x+bb.x, ay=f0.y+bb.y, az=f1.x+bb.z, aw=f1.y+bb.w;
            accb.x += ax*w0.x + ay*w1.x + az*w2.x + aw*w3.x;
            accb.y += ax*w0.y + ay*w1.y + az*w2.y + aw*w3.y;
            accb.z += ax*w0.z + ay*w1.z + az*w2.z + aw*w3.z;
            accb.w += ax*w0.w + ay*w1.w + az*w2.w + aw*w3.w;
        }
    }
    if (oka){
        float dv = dinv[ra];
        __half2 p0 = __floats2half2_rn(acca.x*dv, acca.y*dv);
        __half2 p1 = __floats2half2_rn(acca.z*dv, acca.w*dv);
        uint2 stv; stv.x = *(unsigned*)&p0; stv.y = *(unsigned*)&p1;
        *reinterpret_cast<uint2*>(&y2[(size_t)ra*32 + tc*4]) = stv;
    }
    if (okb){
        float dv = dinv[rb];
        __half2 p0 = __floats2half2_rn(accb.x*dv, accb.y*dv);
        __half2 p1 = __floats2half2_rn(accb.z*dv, accb.w*dv);
        uint2 stv; stv.x = *(unsigned*)&p0; stv.y = *(unsigned*)&p1;
        *reinterpret_cast<uint2*>(&y2[(size_t)rb*32 + tc*4]) = stv;
    }
}

// ---------------- layer-2 aggregation: quarter-wave, zero-row, fp16 accum, 4x ILP ----------------
__global__ void k_agg2h(const __half* __restrict__ y2, const float* __restrict__ dinv,
                        const float* __restrict__ b2, const int* __restrict__ rs,
                        const int* __restrict__ csr, float* __restrict__ Z, int N){
    int wid = (int)((blockIdx.x*blockDim.x + threadIdx.x) >> 6);
    if (wid >= N) return;
    int lane = threadIdx.x & 63;
    int q = lane >> 4, ql = lane & 15;
    int beg = rs[wid], end = rs[wid+1], len = end-beg;
    int qlen = (len + 3) >> 2;                 // wave-uniform
    int qbeg = beg + q*qlen;
    int qend = qbeg + qlen; if (qend > end) qend = end;
    int mylen = qend - qbeg; if (mylen < 0) mylen = 0;
    const __half2* ybase = (const __half2*)(y2) + ql;   // 4B slice of each 64B row
    float sx = 0.f, sy = 0.f;
    int iters = (qlen + 15) >> 4;
    for (int c=0;c<iters;c++){
        int o = c*16 + ql;
        int idx = (o < mylen) ? csr[qbeg + o] : N;   // zero row
        int tmax = qlen - c*16; if (tmax > 16) tmax = 16;
        __half2 a = __float2half2_rn(0.f);
        int tt = 0;
        for (; tt+4 <= tmax; tt += 4){
            int s0 = __shfl(idx, (q<<4)+tt+0);
            int s1 = __shfl(idx, (q<<4)+tt+1);
            int s2 = __shfl(idx, (q<<4)+tt+2);
            int s3 = __shfl(idx, (q<<4)+tt+3);
            __half2 v0 = ybase[(size_t)s0*16];
            __half2 v1 = ybase[(size_t)s1*16];
            __half2 v2 = ybase[(size_t)s2*16];
            __half2 v3 = ybase[(size_t)s3*16];
            a = __hadd2(a, v0); a = __hadd2(a, v1);
            a = __hadd2(a, v2); a = __hadd2(a, v3);
        }
        for (; tt < tmax; ++tt){
            int s = __shfl(idx, (q<<4)+tt);
            a = __hadd2(a, ybase[(size_t)s*16]);
        }
        float2 f = __half22float2(a);
        sx += f.x; sy += f.y;
    }
    sx += __shfl_xor(sx, 16); sy += __shfl_xor(sy, 16);
    sx += __shfl_xor(sx, 32); sy += __shfl_xor(sy, 32);
    if (q==0){
        float2 self = __half22float2(ybase[(size_t)wid*16]);
        sx += self.x; sy += self.y;
        float dv = dinv[wid];
        float2 o;
        o.x = dv*sx + b2[ql*2];
        o.y = dv*sy + b2[ql*2+1];
        *reinterpret_cast<float2*>(&Z[(size_t)wid*32 + ql*2]) = o;
    }
}

// ---------------- + virtual node + softmax (in-place on d_out) ----------------
__global__ void k_softmax(float* __restrict__ Z, const float* __restrict__ r2,
                          const int* __restrict__ batch, int N){
    int r = blockIdx.x*8 + (threadIdx.x>>5);
    int c = threadIdx.x & 31;
    if (r >= N) return;
    float z = Z[(size_t)r*32+c] + r2[batch[r]*32 + c];
    float m = z;
    #pragma unroll
    for (int off=16; off>=1; off>>=1) m = fmaxf(m, __shfl_xor(m, off));
    float e = expf(z - m);
    float s = e;
    #pragma unroll
    for (int off=16; off>=1; off>>=1) s += __shfl_xor(s, off);
    Z[(size_t)r*32+c] = e / s;
}

extern "C" void kernel_launch(void* const* d_in, const int* in_sizes, int n_in,
                              void* d_out, int out_size, void* d_ws, size_t ws_size,
                              hipStream_t stream){
    const float* X   = (const float*)d_in[0];
    const float* W1  = (const float*)d_in[1];
    const float* b1  = (const float*)d_in[2];
    const float* W2  = (const float*)d_in[3];
    const float* b2  = (const float*)d_in[4];
    const float* mW1 = (const float*)d_in[5];
    const float* mb1 = (const float*)d_in[6];
    const float* mW2 = (const float*)d_in[7];
    const float* mb2 = (const float*)d_in[8];
    const int*   ei  = (const int*)d_in[9];
    const int*   batch = (const int*)d_in[10];
    int N = in_sizes[0] / 128;
    int E = in_sizes[9] / 2;
    const int* src = ei;
    const int* dst = ei + E;
    float* Zout = (float*)d_out;

    char* wsp = (char*)d_ws;
    size_t off = 0;
    auto alloc = [&](size_t bytes)->char*{
        char* p = wsp + off; off += (bytes + 255) & ~(size_t)255; return p;
    };
    // zero zone
    int*   bcnt  = (int*)  alloc((size_t)MAXNB*4);
    int*   bfill = (int*)  alloc((size_t)MAXNB*4);
    float* msum  = (float*)alloc((size_t)GNUM*128*4);
    float* msum2 = (float*)alloc((size_t)GNUM*32*4);
    size_t zero_bytes = off;
    // rest
    int*   bbase = (int*)  alloc((size_t)(MAXNB+1)*4);
    int*   deg   = (int*)  alloc((size_t)N*4);
    int*   rs    = (int*)  alloc((size_t)(N+1)*4);
    int*   bsum  = (int*)  alloc(64*4);
    int*   gstart= (int*)  alloc((GNUM+1)*4);
    unsigned* ebuf = (unsigned*)alloc((size_t)E*4);
    int*   csr   = (int*)  alloc((size_t)E*4);
    float* dinvp = (float*)alloc((size_t)N*4);
    __half* yh   = (__half*)alloc((size_t)(N+1)*128*2);   // +1: zero row
    __half* h    = (__half*)alloc((size_t)N*128*2);
    __half* y2h  = (__half*)alloc((size_t)(N+1)*32*2);    // +1: zero row
    float* r1buf = (float*)alloc((size_t)GNUM*128*4);
    float* r2buf = (float*)alloc((size_t)GNUM*32*4);
    (void)ws_size; (void)n_in; (void)out_size;

    hipMemsetAsync(d_ws, 0, zero_bytes, stream);

    int NB = (N + 127) >> 7;            // 391
    int EB = (E + CHUNK-1) / CHUNK;     // 391
    int B1 = (N + 1023)/1024;           // 49 (<= 64)

    k_bucket_hist   <<<EB, 256, 0, stream>>>(dst, E, NB, bcnt);
    k_scan1b        <<<1, 256, 0, stream>>>(bcnt, bbase, NB, E);
    k_bucket_scatter<<<EB, 256, 0, stream>>>(src, dst, E, NB, bbase, bfill, ebuf);
    k_bucket_deg    <<<NB, 256, 0, stream>>>(ebuf, bbase, deg, N);
    k_dinv          <<<(N+255)/256, 256, 0, stream>>>(deg, dinvp, N);
    k_scan_blocks   <<<B1, 256, 0, stream>>>(deg, rs, bsum, N);
    k_scan_mid      <<<1, 64, 0, stream>>>(bsum, B1);
    k_scan_add      <<<B1, 256, 0, stream>>>(rs, bsum, N, E);
    k_bucket_fill   <<<NB, 256, 0, stream>>>(ebuf, bbase, rs, csr, N);

    k_gemm1 <<<(N+31)/32, 256, 0, stream>>>(X, W1, dinvp, yh, N);
    k_agg1  <<<(N+3)/4, 256, 0, stream>>>(yh, dinvp, b1, rs, csr, h, N);

    k_bounds<<<1, 128, 0, stream>>>(batch, N, gstart);
    k_mpoolh<<<dim3(GNUM,8), 64, 0, stream>>>(h, gstart, msum);
    k_mlp1  <<<GNUM, 128, 0, stream>>>(msum, gstart, mW1, mb1, r1buf);

    k_gemm2 <<<(N+63)/64, 256, 0, stream>>>(h, r1buf, batch, W2, dinvp, y2h, N);
    k_agg2h <<<(N+3)/4, 256, 0, stream>>>(y2h, dinvp, b2, rs, csr, Zout, N);

    k_mpool <<<dim3(GNUM,8), 64, 0, stream>>>(Zout, gstart, msum2, 32);
    k_mlp2  <<<GNUM, 64, 0, stream>>>(msum2, gstart, mW2, mb2, r2buf);
    k_softmax<<<(N+7)/8, 256, 0, stream>>>(Zout, r2buf, batch, N);
}